// Round 1
// baseline (747.981 us; speedup 1.0000x reference)
//
#include <hip/hip_runtime.h>
#include <hip/hip_bf16.h>
#include <stdint.h>

// ---------------------------------------------------------------------------
// CCRGNN: 3x GATConv (per-graph, block-local edges) + feature concat + 3-layer MLP
// GNN in fp32 LDS (one graph per workgroup), MLP via bf16 MFMA GEMM.
// Assumptions (flagged for debugging):
//  - edge_index passed as int32 (harness: "integer -> const int*")
//  - mfma bf16 operand = ext_vector_type(8) short (per guide's verified example)
// ---------------------------------------------------------------------------

typedef float f32x4 __attribute__((ext_vector_type(4)));
typedef short bf16x8 __attribute__((ext_vector_type(8)));

// ======================= fused per-graph GNN ===============================

template<int Fin, int Fout>
__device__ __forceinline__ void gat_layer(
    const float* hin, float* Ht, float* hout,
    const float* __restrict__ W, const float* __restrict__ as_,
    const float* __restrict__ ad_, const float* __restrict__ bias,
    const short* sls, const int* off, float* alpha,
    float* sarr, float* darr, int tid)
{
  // h = hin @ W   (pre-bias h used for attention)
  for (int idx = tid; idx < 39 * Fout; idx += 256) {
    int i = idx / Fout, f = idx - i * Fout;
    float acc = 0.f;
#pragma unroll
    for (int k = 0; k < Fin; ++k) acc += hin[i * Fin + k] * W[k * Fout + f];
    Ht[idx] = acc;
  }
  __syncthreads();
  // s_i = h_i . a_src ; d_i = h_i . a_dst
  if (tid < 39) {
    float s = 0.f, d = 0.f;
    for (int f = 0; f < Fout; ++f) { float h = Ht[tid * Fout + f]; s += h * as_[f]; d += h * ad_[f]; }
    sarr[tid] = s; darr[tid] = d;
  }
  __syncthreads();
  // per-dst segment softmax over incoming edges (CSR)
  if (tid < 39) {
    int p0 = off[tid], p1 = off[tid + 1];
    float dv = darr[tid];
    float mx = -1e30f;
    for (int p = p0; p < p1; ++p) {
      float e = sarr[sls[p]] + dv;
      e = (e > 0.f) ? e : 0.2f * e;       // leaky_relu(0.2)
      alpha[p] = e;
      mx = fmaxf(mx, e);
    }
    float den = 0.f;
    for (int p = p0; p < p1; ++p) { float w = expf(alpha[p] - mx); alpha[p] = w; den += w; }
    float inv = 1.f / (den + 1e-16f);
    for (int p = p0; p < p1; ++p) alpha[p] *= inv;
  }
  __syncthreads();
  // out[i] = sum alpha_e * h[src_e] ; + bias ; relu
  for (int idx = tid; idx < 39 * Fout; idx += 256) {
    int i = idx / Fout, f = idx - i * Fout;
    float acc = 0.f;
    int p1 = off[i + 1];
    for (int p = off[i]; p < p1; ++p) acc += alpha[p] * Ht[sls[p] * Fout + f];
    float v = acc + bias[f];
    hout[idx] = (v > 0.f) ? v : 0.f;
  }
  __syncthreads();
}

__global__ __launch_bounds__(256) void gnn_kernel(
    const float* __restrict__ x,
    const int* __restrict__ esrc, const int* __restrict__ edst,
    const float* __restrict__ W1, const float* __restrict__ a1s, const float* __restrict__ a1d, const float* __restrict__ b1,
    const float* __restrict__ W2, const float* __restrict__ a2s, const float* __restrict__ a2d, const float* __restrict__ b2,
    const float* __restrict__ W3, const float* __restrict__ a3s, const float* __restrict__ a3d, const float* __restrict__ b3,
    __hip_bfloat16* __restrict__ fA)
{
  const int b = blockIdx.x, tid = threadIdx.x;
  __shared__ float sx[39];
  __shared__ float h1[39 * 8];
  __shared__ float h2[39 * 64];
  __shared__ float h3[39 * 9];
  __shared__ float Ht[39 * 64];
  __shared__ float sarr[39], darr[39];
  __shared__ float alpha[351];
  __shared__ short sls[351];
  __shared__ int off[40];
  __shared__ int cnt[40];
  __shared__ int cur[40];

  if (tid < 39) { sx[tid] = x[b * 39 + tid]; cnt[tid] = 0; }
  __syncthreads();

  // build CSR by dst: graph b owns global edges [b*312, b*312+312); +39 self loops
  const int ebase = b * 312;
  for (int e = tid; e < 351; e += 256) {
    int ld = (e < 312) ? (edst[ebase + e] - b * 39) : (e - 312);
    atomicAdd(&cnt[ld], 1);
  }
  __syncthreads();
  if (tid == 0) {
    int s = 0;
    for (int i = 0; i < 39; ++i) { off[i] = s; s += cnt[i]; }
    off[39] = s;
  }
  __syncthreads();
  if (tid < 39) cur[tid] = off[tid];
  __syncthreads();
  for (int e = tid; e < 351; e += 256) {
    int ls, ld;
    if (e < 312) { ls = esrc[ebase + e] - b * 39; ld = edst[ebase + e] - b * 39; }
    else         { ls = e - 312; ld = ls; }
    int p = atomicAdd(&cur[ld], 1);
    sls[p] = (short)ls;
  }
  __syncthreads();

  gat_layer<1, 8 >(sx, Ht, h1, W1, a1s, a1d, b1, sls, off, alpha, sarr, darr, tid);
  gat_layer<8, 64>(h1, Ht, h2, W2, a2s, a2d, b2, sls, off, alpha, sarr, darr, tid);
  gat_layer<64, 9>(h2, Ht, h3, W3, a3s, a3d, b3, sls, off, alpha, sarr, darr, tid);

  // feature row: [res(39) res1(312) res2(2496) res3(351) out0(1) out1(8) out2(64) out3(9) pad->3328]
  __hip_bfloat16* fr = fA + (size_t)b * 3328;
  for (int c = tid; c < 39;   c += 256) fr[c]        = __float2bfloat16(sx[c]);
  for (int c = tid; c < 312;  c += 256) fr[39 + c]   = __float2bfloat16(h1[c]);
  for (int c = tid; c < 2496; c += 256) fr[351 + c]  = __float2bfloat16(h2[c]);
  for (int c = tid; c < 351;  c += 256) fr[2847 + c] = __float2bfloat16(h3[c]);
  if (tid < 82) {
    float mx = -1e30f;
    if (tid == 0) {
      for (int i = 0; i < 39; ++i) mx = fmaxf(mx, sx[i]);
      fr[3198] = __float2bfloat16(mx);
    } else if (tid < 9) {
      int f = tid - 1;
      for (int i = 0; i < 39; ++i) mx = fmaxf(mx, h1[i * 8 + f]);
      fr[3199 + f] = __float2bfloat16(mx);
    } else if (tid < 73) {
      int f = tid - 9;
      for (int i = 0; i < 39; ++i) mx = fmaxf(mx, h2[i * 64 + f]);
      fr[3207 + f] = __float2bfloat16(mx);
    } else {
      int f = tid - 73;
      for (int i = 0; i < 39; ++i) mx = fmaxf(mx, h3[i * 9 + f]);
      fr[3271 + f] = __float2bfloat16(mx);
    }
  }
  for (int c = 3280 + tid; c < 3328; c += 256) fr[c] = __float2bfloat16(0.f);
}

// ================= fp32 -> bf16 transposed weight conversion ================
// W [K0,N0] row-major fp32  ->  WT [Np,Kp] row-major bf16 (zero padded)

__global__ __launch_bounds__(256) void conv_transpose(
    const float* __restrict__ W, __hip_bfloat16* __restrict__ WT,
    int K0, int N0, int Kp, int Np)
{
  __shared__ float t[32][33];
  int kb = blockIdx.x * 32, nb = blockIdx.y * 32;
  int tx = threadIdx.x, ty = threadIdx.y;
#pragma unroll
  for (int i = 0; i < 4; ++i) {
    int k = kb + ty + i * 8, n = nb + tx;
    t[ty + i * 8][tx] = (k < K0 && n < N0) ? W[(size_t)k * N0 + n] : 0.0f;
  }
  __syncthreads();
#pragma unroll
  for (int i = 0; i < 4; ++i) {
    int n = nb + ty + i * 8, k = kb + tx;
    WT[(size_t)n * (size_t)Kp + k] = __float2bfloat16(t[tx][ty + i * 8]);
  }
}

// ======================= bf16 MFMA GEMM (m97 structure) =====================
// C[M,Nn] = relu(A[M,K] @ B + bias), B given as BT[Nn,K]. K%64==0, tiles 128x128.
// LDS is fragment-ordered: sub-tile st = mi*2+kk holds a 16x32 operand tile,
// lane L's 16B at st*1024 + L*16 == frag(m=L&15, k=(L>>4)*8..+7). global_load_lds
// dest is wave-uniform base + lane*16 => staging lands exactly in frag order.

__device__ __forceinline__ void gld_lds16(const void* g, void* l) {
  typedef const __attribute__((address_space(1))) unsigned int GU;
  typedef __attribute__((address_space(3))) unsigned int LU;
  __builtin_amdgcn_global_load_lds((GU*)g, (LU*)l, 16, 0, 0);
}

__global__ __launch_bounds__(256) void gemm_bf16(
    const short* __restrict__ A,   // [M,K] bf16
    const short* __restrict__ BT,  // [Nn,K] bf16 (B transposed)
    const float* __restrict__ bias, int Nreal, int doRelu,
    __hip_bfloat16* __restrict__ C, // [M,Nn] bf16
    int M, int Nn, int K)
{
  __shared__ __align__(16) short lA[8192];
  __shared__ __align__(16) short lB[8192];
  const int tid = threadIdx.x;
  const int w = tid >> 6, L = tid & 63;
  const int lrow = L & 15, lch = L >> 4;
  const int m0 = blockIdx.y * 128, n0 = blockIdx.x * 128;
  const int mw = (w >> 1) * 4, nw = (w & 1) * 4;   // wave's 64x64 quadrant

  const short* As = A + (size_t)m0 * K;
  const short* Bs = BT + (size_t)n0 * K;

  f32x4 acc[4][4] = {};

  for (int k0 = 0; k0 < K; k0 += 64) {
#pragma unroll
    for (int j = 0; j < 4; ++j) {
      int st = w + 4 * j;              // wave-uniform sub-tile id
      int mi = st >> 1, kk = st & 1;
      size_t go = (size_t)(mi * 16 + lrow) * K + (size_t)(k0 + kk * 32 + lch * 8);
      gld_lds16(As + go, &lA[st * 512]);
      gld_lds16(Bs + go, &lB[st * 512]);
    }
    __syncthreads();                   // drains vmcnt (global_load_lds) too
#pragma unroll
    for (int kk = 0; kk < 2; ++kk) {
      bf16x8 af[4], bfr[4];
#pragma unroll
      for (int i = 0; i < 4; ++i) {
        af[i]  = *(const bf16x8*)&lA[((mw + i) * 2 + kk) * 512 + L * 8];
        bfr[i] = *(const bf16x8*)&lB[((nw + i) * 2 + kk) * 512 + L * 8];
      }
#pragma unroll
      for (int i = 0; i < 4; ++i)
#pragma unroll
        for (int j = 0; j < 4; ++j)
          acc[i][j] = __builtin_amdgcn_mfma_f32_16x16x32_bf16(af[i], bfr[j], acc[i][j], 0, 0, 0);
    }
    __syncthreads();
  }

  // epilogue: C/D map col=lane&15, row=(lane>>4)*4+r
#pragma unroll
  for (int j = 0; j < 4; ++j) {
    int n = n0 + (nw + j) * 16 + lrow;
    float bn = (n < Nreal) ? bias[n] : 0.f;
#pragma unroll
    for (int i = 0; i < 4; ++i) {
      f32x4 v = acc[i][j];
#pragma unroll
      for (int r = 0; r < 4; ++r) {
        int m = m0 + (mw + i) * 16 + lch * 4 + r;
        float val = v[r] + bn;
        if (doRelu) val = fmaxf(val, 0.f);
        C[(size_t)m * Nn + n] = __float2bfloat16(val);
      }
    }
  }
}

// ================= final 1024->9 GEMM, fp32 out ============================

__global__ __launch_bounds__(256) void gemm3_kernel(
    const __hip_bfloat16* __restrict__ C2,   // [4096,1024]
    const float* __restrict__ W3,            // [1024,9]
    const float* __restrict__ b3,            // [9]
    float* __restrict__ out)                 // [4096,9]
{
  __shared__ float sW3[9 * 1024];
  int tid = threadIdx.x;
  for (int i = tid; i < 9216; i += 256) { int k = i / 9, j = i - 9 * k; sW3[j * 1024 + k] = W3[i]; }
  __syncthreads();
  int row = blockIdx.x * 4 + (tid >> 6);
  int lane = tid & 63;
  const __hip_bfloat16* cr = C2 + (size_t)row * 1024;
  float acc[9] = {0, 0, 0, 0, 0, 0, 0, 0, 0};
  for (int t = 0; t < 16; ++t) {
    int k = lane + 64 * t;               // coalesced C2 reads, conflict-free LDS
    float c = __bfloat162float(cr[k]);
#pragma unroll
    for (int j = 0; j < 9; ++j) acc[j] += c * sW3[j * 1024 + k];
  }
#pragma unroll
  for (int j = 0; j < 9; ++j) {
    float v = acc[j];
    v += __shfl_down(v, 32, 64);
    v += __shfl_down(v, 16, 64);
    v += __shfl_down(v, 8, 64);
    v += __shfl_down(v, 4, 64);
    v += __shfl_down(v, 2, 64);
    v += __shfl_down(v, 1, 64);
    if (lane == 0) out[(size_t)row * 9 + j] = v + b3[j];
  }
}

// ============================= launch =======================================

extern "C" void kernel_launch(void* const* d_in, const int* in_sizes, int n_in,
                              void* d_out, int out_size, void* d_ws, size_t ws_size,
                              hipStream_t stream)
{
  const float* x   = (const float*)d_in[0];
  const int*   ei  = (const int*)d_in[1];
  // d_in[2] = batch_vec (unused; batch = node/39)
  const float* W1  = (const float*)d_in[3];
  const float* a1s = (const float*)d_in[4];
  const float* a1d = (const float*)d_in[5];
  const float* b1  = (const float*)d_in[6];
  const float* W2  = (const float*)d_in[7];
  const float* a2s = (const float*)d_in[8];
  const float* a2d = (const float*)d_in[9];
  const float* b2  = (const float*)d_in[10];
  const float* W3  = (const float*)d_in[11];
  const float* a3s = (const float*)d_in[12];
  const float* a3d = (const float*)d_in[13];
  const float* b3  = (const float*)d_in[14];
  const float* lW1 = (const float*)d_in[15];
  const float* lb1 = (const float*)d_in[16];
  const float* lW2 = (const float*)d_in[17];
  const float* lb2 = (const float*)d_in[18];
  const float* lW3 = (const float*)d_in[19];
  const float* lb3 = (const float*)d_in[20];

  const int E = 4096 * 39 * 8;
  const int* esrc = ei;
  const int* edst = ei + E;

  // workspace layout (bf16 elements); total ~114 MB
  __hip_bfloat16* fA  = (__hip_bfloat16*)d_ws;            // [4096,3328]
  __hip_bfloat16* W1T = fA  + (size_t)4096 * 3328;        // [5120,3328]
  __hip_bfloat16* C1  = W1T + (size_t)5120 * 3328;        // [4096,5120]
  __hip_bfloat16* W2T = C1  + (size_t)4096 * 5120;        // [1024,5120]
  __hip_bfloat16* C2  = fA;                               // alias: fA dead after GEMM1

  conv_transpose<<<dim3(3328 / 32, 5120 / 32), dim3(32, 8), 0, stream>>>(lW1, W1T, 3280, 5000, 3328, 5120);
  conv_transpose<<<dim3(5120 / 32, 1024 / 32), dim3(32, 8), 0, stream>>>(lW2, W2T, 5000, 1024, 5120, 1024);
  gnn_kernel<<<4096, 256, 0, stream>>>(x, esrc, edst,
                                       W1, a1s, a1d, b1, W2, a2s, a2d, b2, W3, a3s, a3d, b3, fA);
  gemm_bf16<<<dim3(40, 32), 256, 0, stream>>>((const short*)fA, (const short*)W1T, lb1, 5000, 1,
                                              C1, 4096, 5120, 3328);
  gemm_bf16<<<dim3(8, 32), 256, 0, stream>>>((const short*)C1, (const short*)W2T, lb2, 1024, 1,
                                             C2, 4096, 1024, 5120);
  gemm3_kernel<<<1024, 256, 0, stream>>>(C2, lW3, lb3, (float*)d_out);
}

// Round 2
// 531.619 us; speedup vs baseline: 1.4070x; 1.4070x over previous
//
#include <hip/hip_runtime.h>
#include <hip/hip_bf16.h>
#include <stdint.h>

// ---------------------------------------------------------------------------
// CCRGNN r2: all GEMM operands pre-swizzled to MFMA-fragment-tiled layout.
// Tiled layout for operand [R rows, K cols] (bf16): block (rt,kt) = 8192 shorts;
//   short index = ((rt*KT + kt)*16 + mi*2 + kq)*512 + (lrow + 16*lch)*8 + j
//   where r = rt*128 + mi*16 + lrow,  k = kt*64 + kq*32 + lch*8 + j.
// Staging inst for sub-tile st reads a CONTIGUOUS 1KiB (lane L at +L*16B) and
// global_load_lds writes LDS base+L*16 -> fragment order, conflict-free reads.
// GEMM2 split-K x2 (fp32 partials) + reduce(bias,relu,bf16) kernel.
// ---------------------------------------------------------------------------

typedef float f32x4 __attribute__((ext_vector_type(4)));
typedef short bf16x8 __attribute__((ext_vector_type(8)));
typedef short s16x4 __attribute__((ext_vector_type(4)));

// ======================= fused per-graph GNN ===============================

template<int Fin, int Fout>
__device__ __forceinline__ void gat_layer(
    const float* hin, float* Ht, float* hout,
    const float* __restrict__ W, const float* __restrict__ as_,
    const float* __restrict__ ad_, const float* __restrict__ bias,
    const short* sls, const int* off, float* alpha,
    float* sarr, float* darr, int tid)
{
  for (int idx = tid; idx < 39 * Fout; idx += 256) {
    int i = idx / Fout, f = idx - i * Fout;
    float acc = 0.f;
#pragma unroll
    for (int k = 0; k < Fin; ++k) acc += hin[i * Fin + k] * W[k * Fout + f];
    Ht[idx] = acc;
  }
  __syncthreads();
  if (tid < 39) {
    float s = 0.f, d = 0.f;
    for (int f = 0; f < Fout; ++f) { float h = Ht[tid * Fout + f]; s += h * as_[f]; d += h * ad_[f]; }
    sarr[tid] = s; darr[tid] = d;
  }
  __syncthreads();
  if (tid < 39) {
    int p0 = off[tid], p1 = off[tid + 1];
    float dv = darr[tid];
    float mx = -1e30f;
    for (int p = p0; p < p1; ++p) {
      float e = sarr[sls[p]] + dv;
      e = (e > 0.f) ? e : 0.2f * e;       // leaky_relu(0.2)
      alpha[p] = e;
      mx = fmaxf(mx, e);
    }
    float den = 0.f;
    for (int p = p0; p < p1; ++p) { float w = expf(alpha[p] - mx); alpha[p] = w; den += w; }
    float inv = 1.f / (den + 1e-16f);
    for (int p = p0; p < p1; ++p) alpha[p] *= inv;
  }
  __syncthreads();
  for (int idx = tid; idx < 39 * Fout; idx += 256) {
    int i = idx / Fout, f = idx - i * Fout;
    float acc = 0.f;
    int p1 = off[i + 1];
    for (int p = off[i]; p < p1; ++p) acc += alpha[p] * Ht[sls[p] * Fout + f];
    float v = acc + bias[f];
    hout[idx] = (v > 0.f) ? v : 0.f;
  }
  __syncthreads();
}

__global__ __launch_bounds__(256) void gnn_kernel(
    const float* __restrict__ x,
    const int* __restrict__ esrc, const int* __restrict__ edst,
    const float* __restrict__ W1, const float* __restrict__ a1s, const float* __restrict__ a1d, const float* __restrict__ b1,
    const float* __restrict__ W2, const float* __restrict__ a2s, const float* __restrict__ a2d, const float* __restrict__ b2,
    const float* __restrict__ W3, const float* __restrict__ a3s, const float* __restrict__ a3d, const float* __restrict__ b3,
    short* __restrict__ fA)   // tiled [4096 rows, 3328 k], KT=52
{
  const int b = blockIdx.x, tid = threadIdx.x;
  __shared__ float feat[3328];   // [res 0-38 | res1 39-350 | res2 351-2846 | res3 2847-3197 | maxes 3198-3279 | pad]
  __shared__ float Ht[39 * 64];
  __shared__ float sarr[39], darr[39];
  __shared__ float alpha[351];
  __shared__ short sls[351];
  __shared__ int off[40];
  __shared__ int cnt[40];
  __shared__ int cur[40];

  float* sx = feat;
  float* h1 = feat + 39;
  float* h2 = feat + 351;
  float* h3 = feat + 2847;

  if (tid < 39) { sx[tid] = x[b * 39 + tid]; cnt[tid] = 0; }
  __syncthreads();

  const int ebase = b * 312;
  for (int e = tid; e < 351; e += 256) {
    int ld = (e < 312) ? (edst[ebase + e] - b * 39) : (e - 312);
    atomicAdd(&cnt[ld], 1);
  }
  __syncthreads();
  if (tid == 0) {
    int s = 0;
    for (int i = 0; i < 39; ++i) { off[i] = s; s += cnt[i]; }
    off[39] = s;
  }
  __syncthreads();
  if (tid < 39) cur[tid] = off[tid];
  __syncthreads();
  for (int e = tid; e < 351; e += 256) {
    int ls, ld;
    if (e < 312) { ls = esrc[ebase + e] - b * 39; ld = edst[ebase + e] - b * 39; }
    else         { ls = e - 312; ld = ls; }
    int p = atomicAdd(&cur[ld], 1);
    sls[p] = (short)ls;
  }
  __syncthreads();

  gat_layer<1, 8 >(sx, Ht, h1, W1, a1s, a1d, b1, sls, off, alpha, sarr, darr, tid);
  gat_layer<8, 64>(h1, Ht, h2, W2, a2s, a2d, b2, sls, off, alpha, sarr, darr, tid);
  gat_layer<64, 9>(h2, Ht, h3, W3, a3s, a3d, b3, sls, off, alpha, sarr, darr, tid);

  // segment-max features
  if (tid < 82) {
    float mx = -1e30f;
    if (tid == 0) {
      for (int i = 0; i < 39; ++i) mx = fmaxf(mx, sx[i]);
      feat[3198] = mx;
    } else if (tid < 9) {
      int f = tid - 1;
      for (int i = 0; i < 39; ++i) mx = fmaxf(mx, h1[i * 8 + f]);
      feat[3199 + f] = mx;
    } else if (tid < 73) {
      int f = tid - 9;
      for (int i = 0; i < 39; ++i) mx = fmaxf(mx, h2[i * 64 + f]);
      feat[3207 + f] = mx;
    } else {
      int f = tid - 73;
      for (int i = 0; i < 39; ++i) mx = fmaxf(mx, h3[i * 9 + f]);
      feat[3271 + f] = mx;
    }
  }
  for (int c = 3280 + tid; c < 3328; c += 256) feat[c] = 0.f;
  __syncthreads();

  // tiled writeout: row b fixed -> rt, mi, lrow fixed; 416 chunks of 8 k each
  const int rt = b >> 7, mi = (b >> 4) & 7, lrow = b & 15;
  for (int c8 = tid; c8 < 416; c8 += 256) {
    int c = c8 * 8;
    int kt = c >> 6, kq = (c >> 5) & 1, lch = (c >> 3) & 3;
    union { bf16x8 v; __hip_bfloat16 h[8]; } z;
#pragma unroll
    for (int jj = 0; jj < 8; ++jj) z.h[jj] = __float2bfloat16(feat[c + jj]);
    size_t addr = ((((size_t)rt * 52 + kt) * 16) + mi * 2 + kq) * 512 + ((size_t)lrow + 16 * lch) * 8;
    *(bf16x8*)&fA[addr] = z.v;
  }
}

// ===== fp32 [K0,N0] row-major -> bf16 fragment-tiled BT [Np rows=n, Kp cols=k]

__global__ __launch_bounds__(256) void conv_tiled(
    const float* __restrict__ W, short* __restrict__ WT,
    int K0, int N0, int KT)     // grid: (Kp/32, Np/32)
{
  __shared__ float t[32][33];
  const int kb = blockIdx.x * 32, nb = blockIdx.y * 32;
  const int tx = threadIdx.x & 31, ty = threadIdx.x >> 5;
#pragma unroll
  for (int i = 0; i < 4; ++i) {
    int k = kb + ty + i * 8, n = nb + tx;
    t[ty + i * 8][tx] = (k < K0 && n < N0) ? W[(size_t)k * N0 + n] : 0.0f;
  }
  __syncthreads();
  const int u = threadIdx.x;
  if (u < 128) {
    int nl = u >> 2, kc = u & 3;          // n-local, k-chunk (8 wide)
    int n = nb + nl, k = kb + kc * 8;
    union { bf16x8 v; __hip_bfloat16 h[8]; } z;
#pragma unroll
    for (int jj = 0; jj < 8; ++jj) z.h[jj] = __float2bfloat16(t[kc * 8 + jj][nl]);
    int rt = n >> 7, mi = (n >> 4) & 7, lr = n & 15;
    int kt = k >> 6, kq = (k >> 5) & 1, lc = (k >> 3) & 3;
    size_t addr = ((((size_t)rt * KT) + kt) * 16 + mi * 2 + kq) * 512 + ((size_t)lr + 16 * lc) * 8;
    *(bf16x8*)&WT[addr] = z.v;
  }
}

// ======================= tiled bf16 MFMA GEMM ==============================

__device__ __forceinline__ void gld_lds16(const void* g, void* l) {
  typedef const __attribute__((address_space(1))) unsigned int GU;
  typedef __attribute__((address_space(3))) unsigned int LU;
  __builtin_amdgcn_global_load_lds((GU*)g, (LU*)l, 16, 0, 0);
}

// MODE 0: C tiled bf16 (as next GEMM's A, outKT = Nn/64), +bias +relu
// MODE 1: fp32 partials P[splits][M][Nn] row-major, no bias/relu
template<int MODE>
__global__ __launch_bounds__(256) void gemm_tiled(
    const short* __restrict__ A, const short* __restrict__ B,
    const float* __restrict__ bias, int Nreal,
    void* __restrict__ Cout, int Nn, int KT, int ktPerSplit, int outKT)
{
  __shared__ __align__(16) short lA[8192];
  __shared__ __align__(16) short lB[8192];
  const int tid = threadIdx.x;
  const int w = tid >> 6, L = tid & 63;
  const int lrow = L & 15, lch = L >> 4;
  const int mt = blockIdx.y, nt = blockIdx.x;
  const int mw = (w >> 1) * 4, nw = (w & 1) * 4;   // wave's 64x64 quadrant
  const int kt0 = blockIdx.z * ktPerSplit, kt1 = kt0 + ktPerSplit;

  const short* Ab = A + ((size_t)mt * KT) * 8192 + (size_t)L * 8;
  const short* Bb = B + ((size_t)nt * KT) * 8192 + (size_t)L * 8;

  f32x4 acc[4][4] = {};

  for (int kt = kt0; kt < kt1; ++kt) {
    const short* Ak = Ab + (size_t)kt * 8192;
    const short* Bk = Bb + (size_t)kt * 8192;
#pragma unroll
    for (int j = 0; j < 4; ++j) {
      int st = w * 4 + j;                // wave loads contiguous 4KB of A and B
      gld_lds16(Ak + st * 512, &lA[st * 512]);
      gld_lds16(Bk + st * 512, &lB[st * 512]);
    }
    __syncthreads();
#pragma unroll
    for (int kk = 0; kk < 2; ++kk) {
      bf16x8 af[4], bfr[4];
#pragma unroll
      for (int i = 0; i < 4; ++i) {
        af[i]  = *(const bf16x8*)&lA[((mw + i) * 2 + kk) * 512 + L * 8];
        bfr[i] = *(const bf16x8*)&lB[((nw + i) * 2 + kk) * 512 + L * 8];
      }
#pragma unroll
      for (int i = 0; i < 4; ++i)
#pragma unroll
        for (int j = 0; j < 4; ++j)
          acc[i][j] = __builtin_amdgcn_mfma_f32_16x16x32_bf16(af[i], bfr[j], acc[i][j], 0, 0, 0);
    }
    __syncthreads();
  }

  if (MODE == 0) {
    // C/D map: col n = lane&15, row m = (lane>>4)*4 + r -> tiled store
    __hip_bfloat16* C = (__hip_bfloat16*)Cout;
#pragma unroll
    for (int j = 0; j < 4; ++j) {
      int n = nt * 128 + (nw + j) * 16 + lrow;
      float bn = (n < Nreal) ? bias[n] : 0.f;
      int kt = n >> 6, kq = (n >> 5) & 1, lc2 = (n >> 3) & 3, j2 = n & 7;
#pragma unroll
      for (int i = 0; i < 4; ++i) {
        int mi = mw + i;
        size_t base = ((((size_t)mt * outKT + kt) * 16) + mi * 2 + kq) * 512
                      + (size_t)(lch * 4) * 8 + (size_t)lc2 * 128 + j2;
#pragma unroll
        for (int r = 0; r < 4; ++r)
          C[base + r * 8] = __float2bfloat16(fmaxf(acc[i][j][r] + bn, 0.f));
      }
    }
  } else {
    float* P = (float*)Cout + (size_t)blockIdx.z * 4096 * 1024;
#pragma unroll
    for (int j = 0; j < 4; ++j) {
      int n = nt * 128 + (nw + j) * 16 + lrow;
#pragma unroll
      for (int i = 0; i < 4; ++i) {
#pragma unroll
        for (int r = 0; r < 4; ++r) {
          int m = mt * 128 + (mw + i) * 16 + lch * 4 + r;
          P[(size_t)m * Nn + n] = acc[i][j][r];
        }
      }
    }
  }
}

// ============ split-K reduce: C2 = bf16(relu(P0+P1+bias)) ==================

__global__ __launch_bounds__(256) void reduce_k(
    const float* __restrict__ P, const float* __restrict__ bias,
    __hip_bfloat16* __restrict__ C2)
{
  int idx = blockIdx.x * 256 + threadIdx.x;          // over 4096*1024/4
  const f32x4* p0 = (const f32x4*)P;
  const f32x4* p1 = p0 + (size_t)4096 * 256;
  f32x4 a = p0[idx], b = p1[idx];
  f32x4 bb = ((const f32x4*)bias)[idx & 255];
  union { s16x4 v; __hip_bfloat16 h[4]; } z;
#pragma unroll
  for (int c = 0; c < 4; ++c) z.h[c] = __float2bfloat16(fmaxf(a[c] + b[c] + bb[c], 0.f));
  *(s16x4*)&C2[(size_t)idx * 4] = z.v;
}

// ================= final 1024->9 GEMM, fp32 out ============================

__global__ __launch_bounds__(256) void gemm3_kernel(
    const __hip_bfloat16* __restrict__ C2,   // [4096,1024] row-major
    const float* __restrict__ W3,            // [1024,9]
    const float* __restrict__ b3,
    float* __restrict__ out)                 // [4096,9]
{
  __shared__ float sW3[9 * 1024];
  int tid = threadIdx.x;
  for (int i = tid; i < 9216; i += 256) { int k = i / 9, j = i - 9 * k; sW3[j * 1024 + k] = W3[i]; }
  __syncthreads();
  int row = blockIdx.x * 4 + (tid >> 6);
  int lane = tid & 63;
  const __hip_bfloat16* cr = C2 + (size_t)row * 1024;
  float acc[9] = {0, 0, 0, 0, 0, 0, 0, 0, 0};
  for (int t = 0; t < 16; ++t) {
    int k = lane + 64 * t;
    float c = __bfloat162float(cr[k]);
#pragma unroll
    for (int j = 0; j < 9; ++j) acc[j] += c * sW3[j * 1024 + k];
  }
#pragma unroll
  for (int j = 0; j < 9; ++j) {
    float v = acc[j];
    v += __shfl_down(v, 32, 64);
    v += __shfl_down(v, 16, 64);
    v += __shfl_down(v, 8, 64);
    v += __shfl_down(v, 4, 64);
    v += __shfl_down(v, 2, 64);
    v += __shfl_down(v, 1, 64);
    if (lane == 0) out[(size_t)row * 9 + j] = v + b3[j];
  }
}

// ============================= launch =======================================

extern "C" void kernel_launch(void* const* d_in, const int* in_sizes, int n_in,
                              void* d_out, int out_size, void* d_ws, size_t ws_size,
                              hipStream_t stream)
{
  const float* x   = (const float*)d_in[0];
  const int*   ei  = (const int*)d_in[1];
  const float* W1  = (const float*)d_in[3];
  const float* a1s = (const float*)d_in[4];
  const float* a1d = (const float*)d_in[5];
  const float* b1  = (const float*)d_in[6];
  const float* W2  = (const float*)d_in[7];
  const float* a2s = (const float*)d_in[8];
  const float* a2d = (const float*)d_in[9];
  const float* b2  = (const float*)d_in[10];
  const float* W3  = (const float*)d_in[11];
  const float* a3s = (const float*)d_in[12];
  const float* a3d = (const float*)d_in[13];
  const float* b3  = (const float*)d_in[14];
  const float* lW1 = (const float*)d_in[15];
  const float* lb1 = (const float*)d_in[16];
  const float* lW2 = (const float*)d_in[17];
  const float* lb2 = (const float*)d_in[18];
  const float* lW3 = (const float*)d_in[19];
  const float* lb3 = (const float*)d_in[20];

  const int E = 4096 * 39 * 8;
  const int* esrc = ei;
  const int* edst = ei + E;

  // ws (bf16 elems): fA 13.6M | W1T 17.0M | C1 21.0M | W2T 5.2M  (~114 MB)
  short* fA  = (short*)d_ws;                       // tiled [4096,3328] KT=52
  short* W1T = fA  + (size_t)4096 * 3328;          // tiled [5120,3328] KT=52
  short* C1  = W1T + (size_t)5120 * 3328;          // tiled [4096,5120] KT=80
  short* W2T = C1  + (size_t)4096 * 5120;          // tiled [1024,5120] KT=80
  // P/C2 alias fA+W1T (dead after GEMM1): P = 2x[4096,1024] fp32, C2 bf16
  float* P = (float*)d_ws;
  __hip_bfloat16* C2 = (__hip_bfloat16*)((float*)d_ws + (size_t)2 * 4096 * 1024);

  conv_tiled<<<dim3(3328 / 32, 5120 / 32), 256, 0, stream>>>(lW1, W1T, 3280, 5000, 52);
  conv_tiled<<<dim3(5120 / 32, 1024 / 32), 256, 0, stream>>>(lW2, W2T, 5000, 1024, 80);
  gnn_kernel<<<4096, 256, 0, stream>>>(x, esrc, edst,
                                       W1, a1s, a1d, b1, W2, a2s, a2d, b2, W3, a3s, a3d, b3, fA);
  // GEMM1: [4096,3328] @ [3328,5120] -> C1 tiled (outKT=80), bias+relu
  gemm_tiled<0><<<dim3(40, 32, 1), 256, 0, stream>>>(fA, W1T, lb1, 5000, C1, 5120, 52, 52, 80);
  // GEMM2: [4096,5120] @ [5120,1024], split-K x2 -> fp32 partials
  gemm_tiled<1><<<dim3(8, 32, 2), 256, 0, stream>>>(C1, W2T, nullptr, 1024, P, 1024, 80, 40, 0);
  reduce_k<<<4096, 256, 0, stream>>>(P, lb2, C2);
  gemm3_kernel<<<1024, 256, 0, stream>>>(C2, lW3, lb3, (float*)d_out);
}